// Round 12
// baseline (1711.381 us; speedup 1.0000x reference)
//
#include <hip/hip_runtime.h>

typedef float v2f __attribute__((ext_vector_type(2)));
typedef float v4f __attribute__((ext_vector_type(4)));

#define KS      11
#define HWDIM   512
#define IMG     (HWDIM*HWDIM)
#define TH      32
#define YSTRIPS 16             // 512 / TH
#define XSTRIPS 5              // 128-col wave strips w/ internal halo
#define PLANES  96             // 32 images * 3 channels
#define WPP     (XSTRIPS*YSTRIPS)   // 80 wave-tasks per plane
#define NWAVES  (PLANES*WPP)        // 7680
#define PPI     (3*WPP)             // 240 partials per image
#define EW      70             // 3 guard + 64 + 3 guard entries per parity array

__device__ __forceinline__ float ssim_px(float mu_u, float mu_v, float Su, float Sv)
{
    const float C1v = 1e-4f, C2v = 9e-4f, EPSV = 1e-8f;
    const float uu = mu_u*mu_u, vv = mu_v*mu_v;
    const float mu2d = 0.5f*(uu - vv);   // 2 mux muy
    const float mu2s = 0.5f*(uu + vv);   // mux^2 + muy^2
    const float Sd   = 0.5f*(Su - Sv);   // 2 conv(p't')
    const float Ss   = 0.5f*(Su + Sv);   // conv(p'^2)+conv(t'^2)
    const float A  = mu2d + C1v;
    const float B  = Sd - mu2d + C2v;
    const float Cc = mu2s + C1v;
    const float D  = Ss - mu2s + C2v;
    // den > 1e-8 always; v_rcp_f32 rel err ~1e-7 << 1.7e-4 threshold
    return A * B * __builtin_amdgcn_rcpf(Cc*D + EPSV);
}

// load input row Y, cols cA,cA+1 (cA even -> aligned float2); u=p'+t', v=p'-t'
#define LOADUV(Y, A, B) do {                                                  \
    if ((unsigned)(Y) < HWDIM) {                                              \
        const v2f p2 = *(const v2f*)(pR + (size_t)(Y)*HWDIM);                 \
        const v2f t2 = *(const v2f*)(tR + (size_t)(Y)*HWDIM);                 \
        A = (v2f){0.5f*(p2.x + t2.x) + 1.0f, 0.5f*(p2.x - t2.x)};             \
        B = (v2f){0.5f*(p2.y + t2.y) + 1.0f, 0.5f*(p2.y - t2.y)};             \
    } else { A = (v2f)(0.f); B = (v2f)(0.f); }                                \
} while(0)

// one vertical tap from ring slot S, both columns, packed (u,v) chains
#define VTAP(W, S) do {                                                       \
    const v2f tA_ = (W) * A##S;                                               \
    mA += tA_;  SA = __builtin_elementwise_fma(tA_, A##S, SA);                \
    const v2f tB_ = (W) * B##S;                                               \
    mB += tB_;  SB = __builtin_elementwise_fma(tB_, B##S, SB);                \
} while(0)

// one horizontal tap: 4-field packed fma (2x v_pk_fma_f32)
#define HF(ACC, W, T)                                                         \
    ACC = __builtin_elementwise_fma((v4f){(W),(W),(W),(W)}, (T), ACC)

// Barrier-free: each WAVE owns a 128-col x-strip (2 cols/lane) whose h-conv
// halo is internal to the strip; private DOUBLE-BUFFERED LDS per wave.
// In-wave DS-pipe ordering is the hardware guarantee; the asm memory clobber
// + sched_barrier(0) is the compiler fence (the r11 bug: per-thread alias
// analysis can't see the cross-lane RAW through LDS and hoisted reads above
// the writes). Double-buffering removes the symmetric WAR hazard (iter r+2's
// writes vs iter r's reads) structurally: they're separated by iter r+1's
// fence and target the other buffer.
__global__ __launch_bounds__(256, 8) void ssim_stream_kernel(
    const float* __restrict__ pred,
    const float* __restrict__ target,
    const float* __restrict__ kern,
    float* __restrict__ partial)
{
    __shared__ v4f bufE[2][4][EW];   // [parity][wave][entry], even local cols
    __shared__ v4f bufO[2][4][EW];   // odd local cols; 17.5 KB total

    const int tid  = threadIdx.x;
    const int wid  = tid >> 6;
    const int lane = tid & 63;
    const int W    = blockIdx.x * 4 + wid;      // 0..7679
    const int plane = W / WPP;
    const int rem   = W - plane * WPP;
    const int ys    = rem / XSTRIPS;
    const int xs    = rem - ys * XSTRIPS;

    // x-strip geometry (wave-uniform): computed cols [base, base+128),
    // valid outputs [out_lo, out_hi). All taps of valid outputs fall inside
    // the computed range or the zero guards (true image edge zero-pad).
    int base, out_lo, out_hi;
    if      (xs == 0) { base = 0;   out_lo = 0;   out_hi = 118; }
    else if (xs == 1) { base = 112; out_lo = 118; out_hi = 235; }
    else if (xs == 2) { base = 230; out_lo = 235; out_hi = 353; }
    else if (xs == 3) { base = 348; out_lo = 353; out_hi = 471; }
    else              { base = 384; out_lo = 471; out_hi = 512; }

    const int y0 = ys * TH;
    const int cA = base + 2*lane;      // even global col of this lane
    const float gA = ((unsigned)(cA     - out_lo) < (unsigned)(out_hi - out_lo)) ? 1.f : 0.f;
    const float gB = ((unsigned)(cA + 1 - out_lo) < (unsigned)(out_hi - out_lo)) ? 1.f : 0.f;

    // exact 1D factors: a_j = k2d[5][j] / sqrt(k2d[5][5]); uniform -> SGPRs
    const float inv_a5 = 1.0f / sqrtf(kern[60]);
    const float w0  = kern[55]*inv_a5,  w1 = kern[56]*inv_a5;
    const float w2  = kern[57]*inv_a5,  w3 = kern[58]*inv_a5;
    const float w4  = kern[59]*inv_a5,  w5 = kern[60]*inv_a5;
    const float w6  = kern[61]*inv_a5,  w7 = kern[62]*inv_a5;
    const float w8  = kern[63]*inv_a5,  w9 = kern[64]*inv_a5;
    const float w10 = kern[65]*inv_a5;

    const float* pR = pred   + (size_t)plane * IMG + cA;
    const float* tR = target + (size_t)plane * IMG + cA;

    // zero the 3+3 guard entries of both parities (own wave writes+reads)
    if (lane < 3) {
        const v4f z = (v4f)(0.f);
        bufE[0][wid][lane] = z;       bufO[0][wid][lane] = z;
        bufE[1][wid][lane] = z;       bufO[1][wid][lane] = z;
        bufE[0][wid][67 + lane] = z;  bufO[0][wid][67 + lane] = z;
        bufE[1][wid][67 + lane] = z;  bufO[1][wid][67 + lane] = z;
    }

    // vertical shift-ring: 11 slots x (u,v) x {colA,colB} — named v2f only
    v2f A0,A1,A2,A3,A4,A5,A6,A7,A8,A9,A10;
    v2f B0,B1,B2,B3,B4,B5,B6,B7,B8,B9,B10;
    v2f nA, nB;

    A0=(v2f)(0.f); B0=(v2f)(0.f);
    LOADUV(y0-5, A1, B1);
    LOADUV(y0-4, A2, B2);
    LOADUV(y0-3, A3, B3);
    LOADUV(y0-2, A4, B4);
    LOADUV(y0-1, A5, B5);
    LOADUV(y0+0, A6, B6);
    LOADUV(y0+1, A7, B7);
    LOADUV(y0+2, A8, B8);
    LOADUV(y0+3, A9, B9);
    LOADUV(y0+4, A10, B10);
    LOADUV(y0+5, nA, nB);

    float lsum = 0.f;
    for (int r = 0; r < TH; ++r) {
        // shift ring down one row
        A0=A1; B0=B1; A1=A2; B1=B2; A2=A3; B2=B3; A3=A4; B3=B4; A4=A5; B4=B5;
        A5=A6; B5=B6; A6=A7; B6=B7; A7=A8; B7=B8; A8=A9; B8=B9; A9=A10; B9=B10;
        A10=nA; B10=nB;
        // prefetch next input row
        LOADUV(y0 + r + 6, nA, nB);

        // vertical 11-tap conv, packed
        v2f mA=(v2f)(0.f), SA=(v2f)(0.f), mB=(v2f)(0.f), SB=(v2f)(0.f);
        VTAP(w0,0);  VTAP(w1,1);  VTAP(w2,2);  VTAP(w3,3);  VTAP(w4,4);
        VTAP(w5,5);  VTAP(w6,6);  VTAP(w7,7);  VTAP(w8,8);  VTAP(w9,9);
        VTAP(w10,10);

        v4f* bE_ = bufE[r & 1][wid];
        v4f* bO_ = bufO[r & 1][wid];
        bE_[3 + lane] = (v4f){mA.x, mA.y, SA.x, SA.y};
        bO_[3 + lane] = (v4f){mB.x, mB.y, SB.x, SB.y};

        // COMPILER FENCE (the r11 fix): cross-lane RAW through LDS is
        // invisible to per-thread alias analysis; forbid hoisting the reads
        // above the writes. Hardware DS-pipe is in-order per wave, so no
        // runtime synchronization is needed.
        asm volatile("" ::: "memory");
        __builtin_amdgcn_sched_barrier(0);

        // horizontal 11-tap conv, window shared across the column pair
        v4f accA = (v4f)(0.f), accB = (v4f)(0.f);
        {
            v4f e, o;
            o = bO_[lane    ]; HF(accA, w0,  o);
            e = bE_[lane + 1]; HF(accA, w1,  e); HF(accB, w0,  e);
            o = bO_[lane + 1]; HF(accA, w2,  o); HF(accB, w1,  o);
            e = bE_[lane + 2]; HF(accA, w3,  e); HF(accB, w2,  e);
            o = bO_[lane + 2]; HF(accA, w4,  o); HF(accB, w3,  o);
            e = bE_[lane + 3]; HF(accA, w5,  e); HF(accB, w4,  e);
            o = bO_[lane + 3]; HF(accA, w6,  o); HF(accB, w5,  o);
            e = bE_[lane + 4]; HF(accA, w7,  e); HF(accB, w6,  e);
            o = bO_[lane + 4]; HF(accA, w8,  o); HF(accB, w7,  o);
            e = bE_[lane + 5]; HF(accA, w9,  e); HF(accB, w8,  e);
            o = bO_[lane + 5]; HF(accA, w10, o); HF(accB, w9,  o);
            e = bE_[lane + 6];                   HF(accB, w10, e);
        }
        lsum = fmaf(gA, ssim_px(accA.x, accA.y, accA.z, accA.w), lsum);
        lsum = fmaf(gB, ssim_px(accB.x, accB.y, accB.z, accB.w), lsum);
    }

    // per-wave reduction only — no cross-wave communication anywhere
    #pragma unroll
    for (int off = 32; off > 0; off >>= 1)
        lsum += __shfl_down(lsum, off, 64);
    if (lane == 0)
        partial[W] = lsum;
}

__global__ __launch_bounds__(64) void ssim_reduce_kernel(
    const float* __restrict__ partial,
    float* __restrict__ out)
{
    const int b    = blockIdx.x;    // image 0..31
    const int lane = threadIdx.x;   // 0..63
    float s = 0.f;
    for (int i = lane; i < PPI; i += 64)
        s += partial[(size_t)b * PPI + i];
    #pragma unroll
    for (int off = 32; off > 0; off >>= 1)
        s += __shfl_down(s, off, 64);
    if (lane == 0) out[b] = s * (1.0f / (3.0f * 512.0f * 512.0f));
}

extern "C" void kernel_launch(void* const* d_in, const int* in_sizes, int n_in,
                              void* d_out, int out_size, void* d_ws, size_t ws_size,
                              hipStream_t stream) {
    (void)in_sizes; (void)n_in; (void)out_size; (void)ws_size;
    const float* pred   = (const float*)d_in[0];
    const float* target = (const float*)d_in[1];
    const float* kern   = (const float*)d_in[2];
    float* out     = (float*)d_out;
    float* partial = (float*)d_ws;   // NWAVES * 4 = 30720 bytes

    ssim_stream_kernel<<<NWAVES/4, 256, 0, stream>>>(pred, target, kern, partial);
    ssim_reduce_kernel<<<32, 64, 0, stream>>>(partial, out);
}

// Round 13
// 99.401 us; speedup vs baseline: 17.2170x; 17.2170x over previous
//
#include <hip/hip_runtime.h>

typedef float v2f __attribute__((ext_vector_type(2)));
typedef float v4f __attribute__((ext_vector_type(4)));

#define KS     11
#define HWDIM  512
#define IMG    (HWDIM*HWDIM)
#define TH     32
#define STRIPS 16              // 512 / TH
#define PLANES 96              // 32 images * 3 channels
#define EG     4               // guard entries (even/odd arrays) each side
#define EOW    264             // EG + 256 + EG
#define NPARTIAL (PLANES*STRIPS)   // 1536

__device__ __forceinline__ float ssim_px(float mu_u, float mu_v, float Su, float Sv)
{
    const float C1v = 1e-4f, C2v = 9e-4f, EPSV = 1e-8f;
    const float uu = mu_u*mu_u, vv = mu_v*mu_v;
    const float mu2d = 0.5f*(uu - vv);   // 2 mux muy
    const float mu2s = 0.5f*(uu + vv);   // mux^2 + muy^2
    const float Sd   = 0.5f*(Su - Sv);   // 2 conv(p't')
    const float Ss   = 0.5f*(Su + Sv);   // conv(p'^2)+conv(t'^2)
    const float A  = mu2d + C1v;
    const float B  = Sd - mu2d + C2v;
    const float Cc = mu2s + C1v;
    const float D  = Ss - mu2s + C2v;
    // den > 1e-8 always; v_rcp_f32 rel err ~1e-7 << 1.7e-4 threshold
    return A * B * __builtin_amdgcn_rcpf(Cc*D + EPSV);
}

// load input row Y, cols 2t,2t+1; A/B = (u,v) per col, u=p'+t', v=p'-t'
#define LOADUV(Y, A, B) do {                                                  \
    if ((unsigned)(Y) < HWDIM) {                                              \
        const v2f p2 = *(const v2f*)(pR + (size_t)(Y)*HWDIM);                 \
        const v2f t2 = *(const v2f*)(tR + (size_t)(Y)*HWDIM);                 \
        A = (v2f){0.5f*(p2.x + t2.x) + 1.0f, 0.5f*(p2.x - t2.x)};             \
        B = (v2f){0.5f*(p2.y + t2.y) + 1.0f, 0.5f*(p2.y - t2.y)};             \
    } else { A = (v2f)(0.f); B = (v2f)(0.f); }                                \
} while(0)

// one vertical tap from ring slot S, both columns; packed (u,v) chains
#define VTAP(W, S) do {                                                       \
    const v2f tA_ = (W) * A##S;                                               \
    mA += tA_;  SA = __builtin_elementwise_fma(tA_, A##S, SA);                \
    const v2f tB_ = (W) * B##S;                                               \
    mB += tB_;  SB = __builtin_elementwise_fma(tB_, B##S, SB);                \
} while(0)

// one horizontal tap: 4-field packed fma (2x v_pk_fma_f32)
#define HF(ACC, W, T)                                                         \
    ACC = __builtin_elementwise_fma((v4f){(W),(W),(W),(W)}, (T), ACC)

__global__ __launch_bounds__(256) void ssim_stream_kernel(
    const float* __restrict__ pred,
    const float* __restrict__ target,
    const float* __restrict__ kern,
    float* __restrict__ partial)
{
    __shared__ v4f hbufE[2][EOW];   // even cols: c=2i -> [EG+i], (mu,mv,Su,Sv)
    __shared__ v4f hbufO[2][EOW];   // odd  cols: c=2i+1 -> [EG+i]
    __shared__ float red[4];

    const int tid   = threadIdx.x;     // 0..255; owns cols 2tid, 2tid+1
    const int strip = blockIdx.x;      // 0..15
    const int plane = blockIdx.y;      // 0..95
    const int y0    = strip * TH;

    // exact 1D factors: a_j = k2d[5][j] / sqrt(k2d[5][5]); uniform -> SGPRs
    const float inv_a5 = 1.0f / sqrtf(kern[60]);
    const float w0  = kern[55]*inv_a5,  w1 = kern[56]*inv_a5;
    const float w2  = kern[57]*inv_a5,  w3 = kern[58]*inv_a5;
    const float w4  = kern[59]*inv_a5,  w5 = kern[60]*inv_a5;
    const float w6  = kern[61]*inv_a5,  w7 = kern[62]*inv_a5;
    const float w8  = kern[63]*inv_a5,  w9 = kern[64]*inv_a5;
    const float w10 = kern[65]*inv_a5;

    const float* pR = pred   + (size_t)plane * IMG + 2*tid;
    const float* tR = target + (size_t)plane * IMG + 2*tid;

    // zero guard entries (cols <0 and >=512), both parities, both arrays;
    // ordered before any h-pass read by the first in-loop barrier
    if (tid < EG) {
        const v4f z = (v4f)(0.f);
        hbufE[0][tid] = z;                 hbufE[1][tid] = z;
        hbufO[0][tid] = z;                 hbufO[1][tid] = z;
        hbufE[0][EG+256+tid] = z;          hbufE[1][EG+256+tid] = z;
        hbufO[0][EG+256+tid] = z;          hbufO[1][EG+256+tid] = z;
    }

    // vertical shift-ring: 11 slots x (u,v)-pair x {colA,colB} — named v2f only
    v2f A0,A1,A2,A3,A4,A5,A6,A7,A8,A9,A10;
    v2f B0,B1,B2,B3,B4,B5,B6,B7,B8,B9,B10;
    v2f nA, nB;

    // entering iteration r=0: slots 1..10 hold rows y0-5..y0+4, prefetch y0+5
    A0 = (v2f)(0.f); B0 = (v2f)(0.f);
    LOADUV(y0-5, A1, B1);
    LOADUV(y0-4, A2, B2);
    LOADUV(y0-3, A3, B3);
    LOADUV(y0-2, A4, B4);
    LOADUV(y0-1, A5, B5);
    LOADUV(y0+0, A6, B6);
    LOADUV(y0+1, A7, B7);
    LOADUV(y0+2, A8, B8);
    LOADUV(y0+3, A9, B9);
    LOADUV(y0+4, A10, B10);
    LOADUV(y0+5, nA, nB);

    float lsum = 0.f;
    for (int r = 0; r < TH; ++r) {
        // shift ring down one row
        A0=A1; B0=B1; A1=A2; B1=B2; A2=A3; B2=B3; A3=A4; B3=B4; A4=A5; B4=B5;
        A5=A6; B5=B6; A6=A7; B6=B7; A7=A8; B7=B8; A8=A9; B8=B9; A9=A10; B9=B10;
        A10=nA; B10=nB;
        // prefetch next input row (consumed next iteration; stays in flight
        // across the relaxed barrier below — the point of this round)
        LOADUV(y0 + r + 6, nA, nB);

        // vertical 11-tap conv, packed: mA=(mu,mv), SA=(Su,Sv) per col
        v2f mA = (v2f)(0.f), SA = (v2f)(0.f);
        v2f mB = (v2f)(0.f), SB = (v2f)(0.f);
        VTAP(w0,0);  VTAP(w1,1);  VTAP(w2,2);  VTAP(w3,3);  VTAP(w4,4);
        VTAP(w5,5);  VTAP(w6,6);  VTAP(w7,7);  VTAP(w8,8);  VTAP(w9,9);
        VTAP(w10,10);

        v4f* bE = &hbufE[r & 1][0];
        v4f* bO = &hbufO[r & 1][0];
        bE[EG + tid] = (v4f){mA.x, mA.y, SA.x, SA.y};
        bO[EG + tid] = (v4f){mB.x, mB.y, SB.x, SB.y};

        // RELAXED BARRIER (vs __syncthreads): drain LDS writes (lgkmcnt) so
        // they're visible to other waves, but do NOT drain vmcnt — the global
        // prefetch stays in flight; its waitcnt lands at the true consumer
        // (next iteration's ring insert). Memory clobbers fence the compiler
        // on both sides (r11 lesson: cross-lane LDS deps are invisible to
        // per-thread alias analysis).
        asm volatile("s_waitcnt lgkmcnt(0)" ::: "memory");
        __builtin_amdgcn_s_barrier();
        asm volatile("" ::: "memory");

        // horizontal 11-tap conv, window shared across the column pair.
        v4f accA = (v4f)(0.f), accB = (v4f)(0.f);
        {
            v4f e, o;
            o = bO[EG + tid - 3]; HF(accA, w0,  o);
            e = bE[EG + tid - 2]; HF(accA, w1,  e); HF(accB, w0,  e);
            o = bO[EG + tid - 2]; HF(accA, w2,  o); HF(accB, w1,  o);
            e = bE[EG + tid - 1]; HF(accA, w3,  e); HF(accB, w2,  e);
            o = bO[EG + tid - 1]; HF(accA, w4,  o); HF(accB, w3,  o);
            e = bE[EG + tid    ]; HF(accA, w5,  e); HF(accB, w4,  e);
            o = bO[EG + tid    ]; HF(accA, w6,  o); HF(accB, w5,  o);
            e = bE[EG + tid + 1]; HF(accA, w7,  e); HF(accB, w6,  e);
            o = bO[EG + tid + 1]; HF(accA, w8,  o); HF(accB, w7,  o);
            e = bE[EG + tid + 2]; HF(accA, w9,  e); HF(accB, w8,  e);
            o = bO[EG + tid + 2]; HF(accA, w10, o); HF(accB, w9,  o);
            e = bE[EG + tid + 3];                   HF(accB, w10, e);
        }
        lsum += ssim_px(accA.x, accA.y, accA.z, accA.w);
        lsum += ssim_px(accB.x, accB.y, accB.z, accB.w);
        // no trailing barrier: parity reuse at r+2 is ordered by barrier r+1
    }

    // deterministic block reduction (4 waves)
    #pragma unroll
    for (int off = 32; off > 0; off >>= 1)
        lsum += __shfl_down(lsum, off, 64);
    if ((tid & 63) == 0) red[tid >> 6] = lsum;
    __syncthreads();
    if (tid == 0)
        partial[plane * STRIPS + strip] = red[0] + red[1] + red[2] + red[3];
}

__global__ __launch_bounds__(64) void ssim_reduce_kernel(
    const float* __restrict__ partial,
    float* __restrict__ out)
{
    const int b    = blockIdx.x;    // image 0..31
    const int lane = threadIdx.x;   // 0..63
    // image b owns partials [48b, 48b+48): planes 3b..3b+2, 16 strips each
    float s = (lane < 48) ? partial[b * 48 + lane] : 0.f;
    #pragma unroll
    for (int off = 32; off > 0; off >>= 1)
        s += __shfl_down(s, off, 64);
    if (lane == 0) out[b] = s * (1.0f / (3.0f * 512.0f * 512.0f));
}

extern "C" void kernel_launch(void* const* d_in, const int* in_sizes, int n_in,
                              void* d_out, int out_size, void* d_ws, size_t ws_size,
                              hipStream_t stream) {
    (void)in_sizes; (void)n_in; (void)out_size; (void)ws_size;
    const float* pred   = (const float*)d_in[0];
    const float* target = (const float*)d_in[1];
    const float* kern   = (const float*)d_in[2];
    float* out     = (float*)d_out;
    float* partial = (float*)d_ws;   // NPARTIAL * 4 = 6144 bytes

    dim3 grid(STRIPS, PLANES);
    ssim_stream_kernel<<<grid, 256, 0, stream>>>(pred, target, kern, partial);
    ssim_reduce_kernel<<<32, 64, 0, stream>>>(partial, out);
}

// Round 14
// 98.746 us; speedup vs baseline: 17.3312x; 1.0066x over previous
//
#include <hip/hip_runtime.h>

typedef float v2f __attribute__((ext_vector_type(2)));
typedef float v4f __attribute__((ext_vector_type(4)));

#define KS     11
#define HWDIM  512
#define IMG    (HWDIM*HWDIM)
#define TH     32
#define STRIPS 16              // 512 / TH
#define PLANES 96              // 32 images * 3 channels
#define EG     4               // guard entries (even/odd arrays) each side
#define EOW    264             // EG + 256 + EG
#define NPARTIAL (PLANES*STRIPS)   // 1536

__device__ __forceinline__ float ssim_px(float mu_u, float mu_v, float Su, float Sv)
{
    const float C1v = 1e-4f, C2v = 9e-4f, EPSV = 1e-8f;
    const float uu = mu_u*mu_u, vv = mu_v*mu_v;
    const float mu2d = 0.5f*(uu - vv);   // 2 mux muy
    const float mu2s = 0.5f*(uu + vv);   // mux^2 + muy^2
    const float Sd   = 0.5f*(Su - Sv);   // 2 conv(p't')
    const float Ss   = 0.5f*(Su + Sv);   // conv(p'^2)+conv(t'^2)
    const float A  = mu2d + C1v;
    const float B  = Sd - mu2d + C2v;
    const float Cc = mu2s + C1v;
    const float D  = Ss - mu2s + C2v;
    // den > 1e-8 always; v_rcp_f32 rel err ~1e-7 << 1.7e-4 threshold
    return A * B * __builtin_amdgcn_rcpf(Cc*D + EPSV);
}

// load input row Y, cols 2t,2t+1; A/B = (u,v) per col, u=p'+t', v=p'-t'
#define LOADUV(Y, A, B) do {                                                  \
    if ((unsigned)(Y) < HWDIM) {                                              \
        const v2f p2 = *(const v2f*)(pR + (size_t)(Y)*HWDIM);                 \
        const v2f t2 = *(const v2f*)(tR + (size_t)(Y)*HWDIM);                 \
        A = (v2f){0.5f*(p2.x + t2.x) + 1.0f, 0.5f*(p2.x - t2.x)};             \
        B = (v2f){0.5f*(p2.y + t2.y) + 1.0f, 0.5f*(p2.y - t2.y)};             \
    } else { A = (v2f)(0.f); B = (v2f)(0.f); }                                \
} while(0)

// one vertical tap from ring slot S into the given accumulators
#define VT(W, S, M_A, S_A, M_B, S_B) do {                                     \
    const v2f tA_ = (W) * A##S;                                               \
    M_A += tA_;  S_A = __builtin_elementwise_fma(tA_, A##S, S_A);             \
    const v2f tB_ = (W) * B##S;                                               \
    M_B += tB_;  S_B = __builtin_elementwise_fma(tB_, B##S, S_B);             \
} while(0)

// one horizontal tap: 4-field packed fma
#define HF(ACC, W, T)                                                         \
    ACC = __builtin_elementwise_fma((v4f){(W),(W),(W),(W)}, (T), ACC)

// full 11-tap horizontal conv for a column pair from buffers BE/BO
#define HCONV(BE, BO) do {                                                    \
    v4f e, o;                                                                 \
    o = BO[EG + tid - 3]; HF(accA, w0,  o);                                   \
    e = BE[EG + tid - 2]; HF(accA, w1,  e); HF(accB, w0,  e);                 \
    o = BO[EG + tid - 2]; HF(accA, w2,  o); HF(accB, w1,  o);                 \
    e = BE[EG + tid - 1]; HF(accA, w3,  e); HF(accB, w2,  e);                 \
    o = BO[EG + tid - 1]; HF(accA, w4,  o); HF(accB, w3,  o);                 \
    e = BE[EG + tid    ]; HF(accA, w5,  e); HF(accB, w4,  e);                 \
    o = BO[EG + tid    ]; HF(accA, w6,  o); HF(accB, w5,  o);                 \
    e = BE[EG + tid + 1]; HF(accA, w7,  e); HF(accB, w6,  e);                 \
    o = BO[EG + tid + 1]; HF(accA, w8,  o); HF(accB, w7,  o);                 \
    e = BE[EG + tid + 2]; HF(accA, w9,  e); HF(accB, w8,  e);                 \
    o = BO[EG + tid + 2]; HF(accA, w10, o); HF(accB, w9,  o);                 \
    e = BE[EG + tid + 3];                   HF(accB, w10, e);                 \
} while(0)

__global__ __launch_bounds__(256) void ssim_stream_kernel(
    const float* __restrict__ pred,
    const float* __restrict__ target,
    const float* __restrict__ kern,
    float* __restrict__ partial)
{
    // fixed buffers: row r (even) -> [0], row r+1 (odd) -> [1]; addresses are
    // compile-time constants (no per-row pointer math)
    __shared__ v4f hbufE[2][EOW];
    __shared__ v4f hbufO[2][EOW];
    __shared__ float red[4];

    const int tid   = threadIdx.x;     // 0..255; owns cols 2tid, 2tid+1
    const int strip = blockIdx.x;      // 0..15
    const int plane = blockIdx.y;      // 0..95
    const int y0    = strip * TH;

    // exact 1D factors: a_j = k2d[5][j] / sqrt(k2d[5][5]); uniform -> SGPRs
    const float inv_a5 = 1.0f / sqrtf(kern[60]);
    const float w0  = kern[55]*inv_a5,  w1 = kern[56]*inv_a5;
    const float w2  = kern[57]*inv_a5,  w3 = kern[58]*inv_a5;
    const float w4  = kern[59]*inv_a5,  w5 = kern[60]*inv_a5;
    const float w6  = kern[61]*inv_a5,  w7 = kern[62]*inv_a5;
    const float w8  = kern[63]*inv_a5,  w9 = kern[64]*inv_a5;
    const float w10 = kern[65]*inv_a5;

    const float* pR = pred   + (size_t)plane * IMG + 2*tid;
    const float* tR = target + (size_t)plane * IMG + 2*tid;

    // zero guard entries (cols <0 and >=512); never overwritten by row writes;
    // ordered before any h-read by the first in-loop barrier
    if (tid < EG) {
        const v4f z = (v4f)(0.f);
        hbufE[0][tid] = z;                 hbufE[1][tid] = z;
        hbufO[0][tid] = z;                 hbufO[1][tid] = z;
        hbufE[0][EG+256+tid] = z;          hbufE[1][EG+256+tid] = z;
        hbufO[0][EG+256+tid] = z;          hbufO[1][EG+256+tid] = z;
    }

    // 12-slot vertical ring x (u,v) x {colA,colB}; processed 2 rows/iteration,
    // shifted by 2 (10 v2f movs per column vs 22 in the 1-row scheme)
    v2f A0,A1,A2,A3,A4,A5,A6,A7,A8,A9,A10,A11;
    v2f B0,B1,B2,B3,B4,B5,B6,B7,B8,B9,B10,B11;
    v2f n0A, n0B, n1A, n1B;

    // entering iteration m=0 (rows 0,1): slots 2..11 hold rows y0-5..y0+4;
    // prefetches hold rows y0+5, y0+6. (S0,S1 are write-only in the shift.)
    LOADUV(y0-5, A2,  B2);
    LOADUV(y0-4, A3,  B3);
    LOADUV(y0-3, A4,  B4);
    LOADUV(y0-2, A5,  B5);
    LOADUV(y0-1, A6,  B6);
    LOADUV(y0+0, A7,  B7);
    LOADUV(y0+1, A8,  B8);
    LOADUV(y0+2, A9,  B9);
    LOADUV(y0+3, A10, B10);
    LOADUV(y0+4, A11, B11);
    LOADUV(y0+5, n0A, n0B);
    LOADUV(y0+6, n1A, n1B);
    A0 = (v2f)(0.f); B0 = (v2f)(0.f); A1 = (v2f)(0.f); B1 = (v2f)(0.f);

    float lsum = 0.f;
    for (int m = 0; m < TH/2; ++m) {
        const int r = 2*m;           // output rows r, r+1
        // shift ring by 2: slots 0..9 <- 2..11; insert prefetched rows
        A0=A2;  B0=B2;  A1=A3;  B1=B3;  A2=A4;  B2=B4;  A3=A5;  B3=B5;
        A4=A6;  B4=B6;  A5=A7;  B5=B7;  A6=A8;  B6=B8;  A7=A9;  B7=B9;
        A8=A10; B8=B10; A9=A11; B9=B11;
        A10=n0A; B10=n0B; A11=n1A; B11=n1B;
        // prefetch the next pair (rows r+7, r+8), consumed next iteration
        LOADUV(y0 + r + 7, n0A, n0B);
        LOADUV(y0 + r + 8, n1A, n1B);

        // vertical conv row r (slots 0..10) and row r+1 (slots 1..11)
        {
            v2f mA=(v2f)(0.f), SA_=(v2f)(0.f), mB=(v2f)(0.f), SB_=(v2f)(0.f);
            VT(w0,0,mA,SA_,mB,SB_);  VT(w1,1,mA,SA_,mB,SB_);
            VT(w2,2,mA,SA_,mB,SB_);  VT(w3,3,mA,SA_,mB,SB_);
            VT(w4,4,mA,SA_,mB,SB_);  VT(w5,5,mA,SA_,mB,SB_);
            VT(w6,6,mA,SA_,mB,SB_);  VT(w7,7,mA,SA_,mB,SB_);
            VT(w8,8,mA,SA_,mB,SB_);  VT(w9,9,mA,SA_,mB,SB_);
            VT(w10,10,mA,SA_,mB,SB_);
            hbufE[0][EG + tid] = (v4f){mA.x, mA.y, SA_.x, SA_.y};
            hbufO[0][EG + tid] = (v4f){mB.x, mB.y, SB_.x, SB_.y};
        }
        {
            v2f mA=(v2f)(0.f), SA_=(v2f)(0.f), mB=(v2f)(0.f), SB_=(v2f)(0.f);
            VT(w0,1,mA,SA_,mB,SB_);  VT(w1,2,mA,SA_,mB,SB_);
            VT(w2,3,mA,SA_,mB,SB_);  VT(w3,4,mA,SA_,mB,SB_);
            VT(w4,5,mA,SA_,mB,SB_);  VT(w5,6,mA,SA_,mB,SB_);
            VT(w6,7,mA,SA_,mB,SB_);  VT(w7,8,mA,SA_,mB,SB_);
            VT(w8,9,mA,SA_,mB,SB_);  VT(w9,10,mA,SA_,mB,SB_);
            VT(w10,11,mA,SA_,mB,SB_);
            hbufE[1][EG + tid] = (v4f){mA.x, mA.y, SA_.x, SA_.y};
            hbufO[1][EG + tid] = (v4f){mB.x, mB.y, SB_.x, SB_.y};
        }

        // make both rows' writes visible; vmcnt NOT drained (prefetch in
        // flight); memory clobbers fence compiler motion (r11 lesson)
        asm volatile("s_waitcnt lgkmcnt(0)" ::: "memory");
        __builtin_amdgcn_s_barrier();
        asm volatile("" ::: "memory");

        // horizontal conv + ssim for both rows
        {
            v4f accA = (v4f)(0.f), accB = (v4f)(0.f);
            HCONV(hbufE[0], hbufO[0]);
            lsum += ssim_px(accA.x, accA.y, accA.z, accA.w);
            lsum += ssim_px(accB.x, accB.y, accB.z, accB.w);
        }
        {
            v4f accA = (v4f)(0.f), accB = (v4f)(0.f);
            HCONV(hbufE[1], hbufO[1]);
            lsum += ssim_px(accA.x, accA.y, accA.z, accA.w);
            lsum += ssim_px(accB.x, accB.y, accB.z, accB.w);
        }

        // bare barrier protects buffers from next iteration's writes; this
        // wave's reads are already drained (their consumers executed). Fences
        // stop the compiler from moving LDS ops across.
        asm volatile("" ::: "memory");
        __builtin_amdgcn_s_barrier();
        asm volatile("" ::: "memory");
    }

    // deterministic block reduction (4 waves)
    #pragma unroll
    for (int off = 32; off > 0; off >>= 1)
        lsum += __shfl_down(lsum, off, 64);
    if ((tid & 63) == 0) red[tid >> 6] = lsum;
    __syncthreads();
    if (tid == 0)
        partial[plane * STRIPS + strip] = red[0] + red[1] + red[2] + red[3];
}

__global__ __launch_bounds__(64) void ssim_reduce_kernel(
    const float* __restrict__ partial,
    float* __restrict__ out)
{
    const int b    = blockIdx.x;    // image 0..31
    const int lane = threadIdx.x;   // 0..63
    // image b owns partials [48b, 48b+48): planes 3b..3b+2, 16 strips each
    float s = (lane < 48) ? partial[b * 48 + lane] : 0.f;
    #pragma unroll
    for (int off = 32; off > 0; off >>= 1)
        s += __shfl_down(s, off, 64);
    if (lane == 0) out[b] = s * (1.0f / (3.0f * 512.0f * 512.0f));
}

extern "C" void kernel_launch(void* const* d_in, const int* in_sizes, int n_in,
                              void* d_out, int out_size, void* d_ws, size_t ws_size,
                              hipStream_t stream) {
    (void)in_sizes; (void)n_in; (void)out_size; (void)ws_size;
    const float* pred   = (const float*)d_in[0];
    const float* target = (const float*)d_in[1];
    const float* kern   = (const float*)d_in[2];
    float* out     = (float*)d_out;
    float* partial = (float*)d_ws;   // NPARTIAL * 4 = 6144 bytes

    dim3 grid(STRIPS, PLANES);
    ssim_stream_kernel<<<grid, 256, 0, stream>>>(pred, target, kern, partial);
    ssim_reduce_kernel<<<32, 64, 0, stream>>>(partial, out);
}

// Round 15
// 97.777 us; speedup vs baseline: 17.5029x; 1.0099x over previous
//
#include <hip/hip_runtime.h>

typedef float v2f __attribute__((ext_vector_type(2)));
typedef float v4f __attribute__((ext_vector_type(4)));

#define KS     11
#define HWDIM  512
#define IMG    (HWDIM*HWDIM)
#define TH     32
#define STRIPS 16              // 512 / TH
#define PLANES 96              // 32 images * 3 channels
#define EG     4               // guard entries (even/odd arrays) each side
#define EOW    264             // EG + 256 + EG
#define NPARTIAL (PLANES*STRIPS)   // 1536

__device__ __forceinline__ float ssim_px(float mu_u, float mu_v, float Su, float Sv)
{
    const float C1v = 1e-4f, C2v = 9e-4f, EPSV = 1e-8f;
    const float uu = mu_u*mu_u, vv = mu_v*mu_v;
    const float mu2d = 0.5f*(uu - vv);   // 2 mux muy
    const float mu2s = 0.5f*(uu + vv);   // mux^2 + muy^2
    const float Sd   = 0.5f*(Su - Sv);   // 2 conv(p't')
    const float Ss   = 0.5f*(Su + Sv);   // conv(p'^2)+conv(t'^2)
    const float A  = mu2d + C1v;
    const float B  = Sd - mu2d + C2v;
    const float Cc = mu2s + C1v;
    const float D  = Ss - mu2s + C2v;
    // den > 1e-8 always; v_rcp_f32 rel err ~1e-7 << 1.7e-4 threshold
    return A * B * __builtin_amdgcn_rcpf(Cc*D + EPSV);
}

// load input row Y, cols 2t,2t+1; A/B = (u,v) per col, u=p'+t', v=p'-t'
#define LOADUV(Y, A, B) do {                                                  \
    if ((unsigned)(Y) < HWDIM) {                                              \
        const v2f p2 = *(const v2f*)(pR + (size_t)(Y)*HWDIM);                 \
        const v2f t2 = *(const v2f*)(tR + (size_t)(Y)*HWDIM);                 \
        A = (v2f){0.5f*(p2.x + t2.x) + 1.0f, 0.5f*(p2.x - t2.x)};             \
        B = (v2f){0.5f*(p2.y + t2.y) + 1.0f, 0.5f*(p2.y - t2.y)};             \
    } else { A = (v2f)(0.f); B = (v2f)(0.f); }                                \
} while(0)

// one vertical tap from ring slot S into the given accumulators
#define VT(W, S, M_A, S_A, M_B, S_B) do {                                     \
    const v2f tA_ = (W) * A##S;                                               \
    M_A += tA_;  S_A = __builtin_elementwise_fma(tA_, A##S, S_A);             \
    const v2f tB_ = (W) * B##S;                                               \
    M_B += tB_;  S_B = __builtin_elementwise_fma(tB_, B##S, S_B);             \
} while(0)

// one horizontal tap: 4-field packed fma
#define HF(ACC, W, T)                                                         \
    ACC = __builtin_elementwise_fma((v4f){(W),(W),(W),(W)}, (T), ACC)

// full 11-tap horizontal conv for a column pair from buffers BE/BO
#define HCONV(BE, BO) do {                                                    \
    v4f e, o;                                                                 \
    o = BO[EG + tid - 3]; HF(accA, w0,  o);                                   \
    e = BE[EG + tid - 2]; HF(accA, w1,  e); HF(accB, w0,  e);                 \
    o = BO[EG + tid - 2]; HF(accA, w2,  o); HF(accB, w1,  o);                 \
    e = BE[EG + tid - 1]; HF(accA, w3,  e); HF(accB, w2,  e);                 \
    o = BO[EG + tid - 1]; HF(accA, w4,  o); HF(accB, w3,  o);                 \
    e = BE[EG + tid    ]; HF(accA, w5,  e); HF(accB, w4,  e);                 \
    o = BO[EG + tid    ]; HF(accA, w6,  o); HF(accB, w5,  o);                 \
    e = BE[EG + tid + 1]; HF(accA, w7,  e); HF(accB, w6,  e);                 \
    o = BO[EG + tid + 1]; HF(accA, w8,  o); HF(accB, w7,  o);                 \
    e = BE[EG + tid + 2]; HF(accA, w9,  e); HF(accB, w8,  e);                 \
    o = BO[EG + tid + 2]; HF(accA, w10, o); HF(accB, w9,  o);                 \
    e = BE[EG + tid + 3];                   HF(accB, w10, e);                 \
} while(0)

__global__ __launch_bounds__(256) void ssim_stream_kernel(
    const float* __restrict__ pred,
    const float* __restrict__ target,
    const float* __restrict__ kern,
    float* __restrict__ partial)
{
    // fixed buffers: row r (even) -> [0], row r+1 (odd) -> [1]; addresses are
    // compile-time constants (no per-row pointer math)
    __shared__ v4f hbufE[2][EOW];
    __shared__ v4f hbufO[2][EOW];
    __shared__ float red[4];

    const int tid   = threadIdx.x;     // 0..255; owns cols 2tid, 2tid+1
    const int strip = blockIdx.x;      // 0..15
    const int plane = blockIdx.y;      // 0..95
    const int y0    = strip * TH;

    // exact 1D factors: a_j = k2d[5][j] / sqrt(k2d[5][5]); uniform -> SGPRs
    const float inv_a5 = 1.0f / sqrtf(kern[60]);
    const float w0  = kern[55]*inv_a5,  w1 = kern[56]*inv_a5;
    const float w2  = kern[57]*inv_a5,  w3 = kern[58]*inv_a5;
    const float w4  = kern[59]*inv_a5,  w5 = kern[60]*inv_a5;
    const float w6  = kern[61]*inv_a5,  w7 = kern[62]*inv_a5;
    const float w8  = kern[63]*inv_a5,  w9 = kern[64]*inv_a5;
    const float w10 = kern[65]*inv_a5;

    const float* pR = pred   + (size_t)plane * IMG + 2*tid;
    const float* tR = target + (size_t)plane * IMG + 2*tid;

    // zero guard entries (cols <0 and >=512); never overwritten by row writes;
    // ordered before any h-read by the first in-loop barrier
    if (tid < EG) {
        const v4f z = (v4f)(0.f);
        hbufE[0][tid] = z;                 hbufE[1][tid] = z;
        hbufO[0][tid] = z;                 hbufO[1][tid] = z;
        hbufE[0][EG+256+tid] = z;          hbufE[1][EG+256+tid] = z;
        hbufO[0][EG+256+tid] = z;          hbufO[1][EG+256+tid] = z;
    }

    // 12-slot vertical ring x (u,v) x {colA,colB}; processed 2 rows/iteration,
    // shifted by 2 (10 v2f movs per column vs 22 in the 1-row scheme)
    v2f A0,A1,A2,A3,A4,A5,A6,A7,A8,A9,A10,A11;
    v2f B0,B1,B2,B3,B4,B5,B6,B7,B8,B9,B10,B11;
    v2f n0A, n0B, n1A, n1B;

    // entering iteration m=0 (rows 0,1): slots 2..11 hold rows y0-5..y0+4;
    // prefetches hold rows y0+5, y0+6. (S0,S1 are write-only in the shift.)
    LOADUV(y0-5, A2,  B2);
    LOADUV(y0-4, A3,  B3);
    LOADUV(y0-3, A4,  B4);
    LOADUV(y0-2, A5,  B5);
    LOADUV(y0-1, A6,  B6);
    LOADUV(y0+0, A7,  B7);
    LOADUV(y0+1, A8,  B8);
    LOADUV(y0+2, A9,  B9);
    LOADUV(y0+3, A10, B10);
    LOADUV(y0+4, A11, B11);
    LOADUV(y0+5, n0A, n0B);
    LOADUV(y0+6, n1A, n1B);
    A0 = (v2f)(0.f); B0 = (v2f)(0.f); A1 = (v2f)(0.f); B1 = (v2f)(0.f);

    float lsum = 0.f;
    for (int m = 0; m < TH/2; ++m) {
        const int r = 2*m;           // output rows r, r+1
        // shift ring by 2: slots 0..9 <- 2..11; insert prefetched rows
        A0=A2;  B0=B2;  A1=A3;  B1=B3;  A2=A4;  B2=B4;  A3=A5;  B3=B5;
        A4=A6;  B4=B6;  A5=A7;  B5=B7;  A6=A8;  B6=B8;  A7=A9;  B7=B9;
        A8=A10; B8=B10; A9=A11; B9=B11;
        A10=n0A; B10=n0B; A11=n1A; B11=n1B;
        // prefetch the next pair (rows r+7, r+8), consumed next iteration
        LOADUV(y0 + r + 7, n0A, n0B);
        LOADUV(y0 + r + 8, n1A, n1B);

        // vertical conv row r (slots 0..10) and row r+1 (slots 1..11)
        {
            v2f mA=(v2f)(0.f), SA_=(v2f)(0.f), mB=(v2f)(0.f), SB_=(v2f)(0.f);
            VT(w0,0,mA,SA_,mB,SB_);  VT(w1,1,mA,SA_,mB,SB_);
            VT(w2,2,mA,SA_,mB,SB_);  VT(w3,3,mA,SA_,mB,SB_);
            VT(w4,4,mA,SA_,mB,SB_);  VT(w5,5,mA,SA_,mB,SB_);
            VT(w6,6,mA,SA_,mB,SB_);  VT(w7,7,mA,SA_,mB,SB_);
            VT(w8,8,mA,SA_,mB,SB_);  VT(w9,9,mA,SA_,mB,SB_);
            VT(w10,10,mA,SA_,mB,SB_);
            hbufE[0][EG + tid] = (v4f){mA.x, mA.y, SA_.x, SA_.y};
            hbufO[0][EG + tid] = (v4f){mB.x, mB.y, SB_.x, SB_.y};
        }
        {
            v2f mA=(v2f)(0.f), SA_=(v2f)(0.f), mB=(v2f)(0.f), SB_=(v2f)(0.f);
            VT(w0,1,mA,SA_,mB,SB_);  VT(w1,2,mA,SA_,mB,SB_);
            VT(w2,3,mA,SA_,mB,SB_);  VT(w3,4,mA,SA_,mB,SB_);
            VT(w4,5,mA,SA_,mB,SB_);  VT(w5,6,mA,SA_,mB,SB_);
            VT(w6,7,mA,SA_,mB,SB_);  VT(w7,8,mA,SA_,mB,SB_);
            VT(w8,9,mA,SA_,mB,SB_);  VT(w9,10,mA,SA_,mB,SB_);
            VT(w10,11,mA,SA_,mB,SB_);
            hbufE[1][EG + tid] = (v4f){mA.x, mA.y, SA_.x, SA_.y};
            hbufO[1][EG + tid] = (v4f){mB.x, mB.y, SB_.x, SB_.y};
        }

        // make both rows' writes visible; vmcnt NOT drained (prefetch in
        // flight); memory clobbers fence compiler motion (r11 lesson)
        asm volatile("s_waitcnt lgkmcnt(0)" ::: "memory");
        __builtin_amdgcn_s_barrier();
        asm volatile("" ::: "memory");

        // horizontal conv + ssim for both rows
        {
            v4f accA = (v4f)(0.f), accB = (v4f)(0.f);
            HCONV(hbufE[0], hbufO[0]);
            lsum += ssim_px(accA.x, accA.y, accA.z, accA.w);
            lsum += ssim_px(accB.x, accB.y, accB.z, accB.w);
        }
        {
            v4f accA = (v4f)(0.f), accB = (v4f)(0.f);
            HCONV(hbufE[1], hbufO[1]);
            lsum += ssim_px(accA.x, accA.y, accA.z, accA.w);
            lsum += ssim_px(accB.x, accB.y, accB.z, accB.w);
        }

        // bare barrier protects buffers from next iteration's writes; this
        // wave's reads are already drained (their consumers executed). Fences
        // stop the compiler from moving LDS ops across.
        asm volatile("" ::: "memory");
        __builtin_amdgcn_s_barrier();
        asm volatile("" ::: "memory");
    }

    // deterministic block reduction (4 waves)
    #pragma unroll
    for (int off = 32; off > 0; off >>= 1)
        lsum += __shfl_down(lsum, off, 64);
    if ((tid & 63) == 0) red[tid >> 6] = lsum;
    __syncthreads();
    if (tid == 0)
        partial[plane * STRIPS + strip] = red[0] + red[1] + red[2] + red[3];
}

__global__ __launch_bounds__(64) void ssim_reduce_kernel(
    const float* __restrict__ partial,
    float* __restrict__ out)
{
    const int b    = blockIdx.x;    // image 0..31
    const int lane = threadIdx.x;   // 0..63
    // image b owns partials [48b, 48b+48): planes 3b..3b+2, 16 strips each
    float s = (lane < 48) ? partial[b * 48 + lane] : 0.f;
    #pragma unroll
    for (int off = 32; off > 0; off >>= 1)
        s += __shfl_down(s, off, 64);
    if (lane == 0) out[b] = s * (1.0f / (3.0f * 512.0f * 512.0f));
}

extern "C" void kernel_launch(void* const* d_in, const int* in_sizes, int n_in,
                              void* d_out, int out_size, void* d_ws, size_t ws_size,
                              hipStream_t stream) {
    (void)in_sizes; (void)n_in; (void)out_size; (void)ws_size;
    const float* pred   = (const float*)d_in[0];
    const float* target = (const float*)d_in[1];
    const float* kern   = (const float*)d_in[2];
    float* out     = (float*)d_out;
    float* partial = (float*)d_ws;   // NPARTIAL * 4 = 6144 bytes

    dim3 grid(STRIPS, PLANES);
    ssim_stream_kernel<<<grid, 256, 0, stream>>>(pred, target, kern, partial);
    ssim_reduce_kernel<<<32, 64, 0, stream>>>(partial, out);
}